// Round 1
// baseline (219.993 us; speedup 1.0000x reference)
//
#include <hip/hip_runtime.h>
#include <hip/hip_bf16.h>

typedef __attribute__((ext_vector_type(8))) short bf16x8;
typedef __attribute__((ext_vector_type(4))) float f32x4;
typedef __attribute__((ext_vector_type(4))) unsigned int u32x4;

#define NNODES 8192
#define NEDGES 65536
#define FIN 256
#define FOUT 64
#define EDIM 32

// workspace byte offsets
#define WS_HN    0u         // 8192*64*4   = 2 MB
#define WS_HS    2097152u   // 2 MB
#define WS_AGG   4194304u   // 2 MB
#define WS_DEG   6291456u   // 8192*4 = 32 KB (int)
#define WS_WBF   6324224u   // 4096*32*2 = 256 KB (bf16 W_edge)
#define WS_WPRET 6586368u   // 256*64*4 = 64 KB
#define WS_WST   6651904u   // 64*64*4 = 16 KB
#define WS_WNT   6668288u   // 16 KB

__device__ __forceinline__ unsigned short f2bf(float f) {
    unsigned u = __builtin_bit_cast(unsigned, f);
    u = (u + 0x7fffu + ((u >> 16) & 1u)) >> 16;   // RNE
    return (unsigned short)u;
}

// ---------------- prep: bf16-cast W_edge, transpose the small weights ----------------
__global__ void prep_kernel(const float* __restrict__ W_edge,
                            const float* __restrict__ W_preagg,
                            const float* __restrict__ W_self,
                            const float* __restrict__ W_neigh,
                            unsigned short* __restrict__ wbf,
                            float* __restrict__ wpreT,
                            float* __restrict__ wsT,
                            float* __restrict__ wnT) {
    int i = blockIdx.x * 256 + threadIdx.x;
    if (i < FOUT * FOUT * EDIM) wbf[i] = f2bf(W_edge[i]);            // 131072
    if (i < FOUT * FIN) {                                            // 16384
        int o = i >> 8, k = i & 255;
        wpreT[k * FOUT + o] = W_preagg[i];
    }
    if (i < FOUT * FOUT) {                                           // 4096
        int o = i >> 6, k = i & 63;
        wsT[k * FOUT + o] = W_self[i];
        wnT[k * FOUT + o] = W_neigh[i];
    }
}

// ---------------- preagg: hn = relu(h_neigh @ Wp^T), hs = relu(h_self @ Wp^T) --------
__global__ __launch_bounds__(256) void preagg_kernel(const float* __restrict__ h_neigh,
                                                     const float* __restrict__ h_self,
                                                     const float* __restrict__ wpreT,
                                                     float* __restrict__ hn,
                                                     float* __restrict__ hs) {
    __shared__ float hrow[4 * FIN];           // 4 rows x 256
    const float* srcp = blockIdx.y ? h_self : h_neigh;
    float* outp = blockIdx.y ? hs : hn;
    int t = threadIdx.x;
    int row0 = blockIdx.x * 4;
    reinterpret_cast<float4*>(hrow)[t] =
        reinterpret_cast<const float4*>(srcp + (size_t)row0 * FIN)[t];
    __syncthreads();
    int r = t >> 6, o = t & 63;
    const float* hr = hrow + r * FIN;
    float acc = 0.f;
    #pragma unroll 8
    for (int k = 0; k < FIN; ++k)
        acc = fmaf(hr[k], wpreT[k * FOUT + o], acc);   // coalesced 256B/wave reads
    outp[(size_t)(row0 + r) * FOUT + o] = fmaxf(acc, 0.f);
}

// ---------------- edge: fused edge-MLP GEMM + relu + i-sum + u_mul_e + scatter -------
// wave = 32 edges (2 MFMA M-tiles); block = 4 waves = 128 edges; grid = 512
// W_edge (bf16, 256KB) streamed through LDS in 4 chunks of 64KB (2 blocks/CU)
#define CHUNK_NB 64

__global__ __launch_bounds__(256, 2) void edge_kernel(
    const float* __restrict__ ef,
    const unsigned short* __restrict__ wbf,
    const float* __restrict__ b_edge,
    const float* __restrict__ hn,
    const int* __restrict__ src,
    const int* __restrict__ dst,
    float* __restrict__ agg,
    int* __restrict__ deg) {
    __shared__ __align__(16) unsigned short bsm[CHUNK_NB * 16 * EDIM];   // 64 KB
    int tid = threadIdx.x;
    int wave = tid >> 6, lane = tid & 63;
    int rowm = lane & 15, kc = lane >> 4, k0 = kc * 8;
    int e0 = blockIdx.x * 128 + wave * 32;

    // A fragments: lane holds ef[row = e0+t*16+(lane&15)][k = (lane>>4)*8 .. +8)
    bf16x8 a[2];
    #pragma unroll
    for (int t = 0; t < 2; ++t) {
        const float* p = ef + (size_t)(e0 + t * 16 + rowm) * EDIM + k0;
        float4 v0 = reinterpret_cast<const float4*>(p)[0];
        float4 v1 = reinterpret_cast<const float4*>(p)[1];
        bf16x8 aa;
        aa[0] = (short)f2bf(v0.x); aa[1] = (short)f2bf(v0.y);
        aa[2] = (short)f2bf(v0.z); aa[3] = (short)f2bf(v0.w);
        aa[4] = (short)f2bf(v1.x); aa[5] = (short)f2bf(v1.y);
        aa[6] = (short)f2bf(v1.z); aa[7] = (short)f2bf(v1.w);
        a[t] = aa;
    }

    // s accumulators: sacc[tile][jblk] , jblk = (column_block & 3), j = jblk*16 + rowm
    f32x4 sacc[2][4];
    #pragma unroll
    for (int t = 0; t < 2; ++t)
        #pragma unroll
        for (int j = 0; j < 4; ++j)
            sacc[t][j] = f32x4{0.f, 0.f, 0.f, 0.f};

    for (int ch = 0; ch < 4; ++ch) {
        __syncthreads();
        {   // stage 64KB of W_edge(bf16): coalesced 16B per thread x16
            const u32x4* g = reinterpret_cast<const u32x4*>(wbf) + ch * 4096;
            u32x4* l = reinterpret_cast<u32x4*>(bsm);
            #pragma unroll
            for (int it = 0; it < 16; ++it)
                l[tid + 256 * it] = g[tid + 256 * it];
        }
        __syncthreads();
        const float* bias_p = b_edge + ch * (CHUNK_NB * 16) + rowm;
        for (int nbl = 0; nbl < CHUNK_NB; nbl += 4) {
            #pragma unroll
            for (int u = 0; u < 4; ++u) {
                // B frag: lane holds W_edge[c = nb*16+(lane&15)][k0..k0+8)  (B = W^T)
                bf16x8 b = *reinterpret_cast<const bf16x8*>(
                    bsm + ((nbl + u) * 16 + rowm) * EDIM + k0);
                float bias = bias_p[(nbl + u) * 16];
                f32x4 cin = {bias, bias, bias, bias};   // bias folded into C operand
                #pragma unroll
                for (int t = 0; t < 2; ++t) {
                    f32x4 d = __builtin_amdgcn_mfma_f32_16x16x32_bf16(a[t], b, cin, 0, 0, 0);
                    sacc[t][u][0] += fmaxf(d[0], 0.f);
                    sacc[t][u][1] += fmaxf(d[1], 0.f);
                    sacc[t][u][2] += fmaxf(d[2], 0.f);
                    sacc[t][u][3] += fmaxf(d[3], 0.f);
                }
            }
        }
    }

    // scatter: C/D layout col=lane&15, row=(lane>>4)*4+reg
    #pragma unroll
    for (int t = 0; t < 2; ++t) {
        #pragma unroll
        for (int r = 0; r < 4; ++r) {
            int e = e0 + t * 16 + kc * 4 + r;
            int se = src[e], de = dst[e];
            if (rowm == 0) atomicAdd(deg + de, 1);
            #pragma unroll
            for (int jb = 0; jb < 4; ++jb) {
                int j = jb * 16 + rowm;
                float v = sacc[t][jb][r] * hn[(size_t)se * FOUT + j];
                atomicAdd(agg + (size_t)de * FOUT + j, v);   // 64B-coalesced per 1/4-wave
            }
        }
    }
}

// ---------------- final: neigh = agg/max(deg,1); z = relu(relu(hs@Ws^T)+relu(neigh@Wn^T))
__global__ __launch_bounds__(256) void final_kernel(
    const float* __restrict__ hs,
    const float* __restrict__ agg,
    const int* __restrict__ deg,
    const float* __restrict__ wsT,
    const float* __restrict__ wnT,
    float* __restrict__ out) {
    __shared__ float hsr[4 * FOUT];
    __shared__ float ngr[4 * FOUT];
    int t = threadIdx.x, r = t >> 6, o = t & 63;
    int row = blockIdx.x * 4 + r;
    float dg = (float)deg[row];
    float rd = 1.f / fmaxf(dg, 1.f);
    hsr[t] = hs[(size_t)row * FOUT + o];
    ngr[t] = agg[(size_t)row * FOUT + o] * rd;
    __syncthreads();
    const float* hp = hsr + r * FOUT;
    const float* np = ngr + r * FOUT;
    float a1 = 0.f, a2 = 0.f;
    #pragma unroll 8
    for (int k = 0; k < FOUT; ++k) {
        a1 = fmaf(hp[k], wsT[k * FOUT + o], a1);
        a2 = fmaf(np[k], wnT[k * FOUT + o], a2);
    }
    out[(size_t)row * FOUT + o] = fmaxf(fmaxf(a1, 0.f) + fmaxf(a2, 0.f), 0.f);
}

extern "C" void kernel_launch(void* const* d_in, const int* in_sizes, int n_in,
                              void* d_out, int out_size, void* d_ws, size_t ws_size,
                              hipStream_t stream) {
    const float* h_neigh  = (const float*)d_in[0];
    const float* h_self   = (const float*)d_in[1];
    const float* ef       = (const float*)d_in[2];
    const float* W_preagg = (const float*)d_in[3];
    const float* W_self   = (const float*)d_in[4];
    const float* W_neigh  = (const float*)d_in[5];
    const float* W_edge   = (const float*)d_in[6];
    const float* b_edge   = (const float*)d_in[7];
    const int*   src      = (const int*)d_in[8];
    const int*   dst      = (const int*)d_in[9];
    float* out = (float*)d_out;
    char* ws = (char*)d_ws;

    float* hn    = (float*)(ws + WS_HN);
    float* hs    = (float*)(ws + WS_HS);
    float* agg   = (float*)(ws + WS_AGG);
    int*   deg   = (int*)(ws + WS_DEG);
    unsigned short* wbf = (unsigned short*)(ws + WS_WBF);
    float* wpreT = (float*)(ws + WS_WPRET);
    float* wsT   = (float*)(ws + WS_WST);
    float* wnT   = (float*)(ws + WS_WNT);

    // zero agg + deg (contiguous) every call — harness does not re-poison
    hipMemsetAsync(ws + WS_AGG, 0, 2097152u + 32768u, stream);

    prep_kernel<<<512, 256, 0, stream>>>(W_edge, W_preagg, W_self, W_neigh,
                                         wbf, wpreT, wsT, wnT);
    preagg_kernel<<<dim3(2048, 2), 256, 0, stream>>>(h_neigh, h_self, wpreT, hn, hs);
    edge_kernel<<<512, 256, 0, stream>>>(ef, wbf, b_edge, hn, src, dst, agg, deg);
    final_kernel<<<2048, 256, 0, stream>>>(hs, agg, deg, wsT, wnT, out);
}

// Round 2
// 217.100 us; speedup vs baseline: 1.0133x; 1.0133x over previous
//
#include <hip/hip_runtime.h>
#include <hip/hip_bf16.h>

typedef __attribute__((ext_vector_type(8))) short bf16x8;
typedef __attribute__((ext_vector_type(4))) float f32x4;
typedef __attribute__((ext_vector_type(4))) unsigned int u32x4;

#define NNODES 8192
#define NEDGES 65536
#define FIN 256
#define FOUT 64
#define EDIM 32

// workspace byte offsets
#define WS_HN    0x000000u   // 8192*64*4 = 2 MB
#define WS_HS    0x200000u   // 2 MB
#define WS_MSG   0x400000u   // 65536*64*4 = 16 MB
#define WS_DEG   0x1400000u  // 8192*4 = 32 KB
#define WS_OFF   0x1408000u  // 32 KB
#define WS_RANK  0x1410000u  // 65536*4 = 256 KB
#define WS_WBF   0x1450000u  // 4096*32*2 = 256 KB
#define WS_WPRET 0x1490000u  // 256*64*4 = 64 KB
#define WS_WST   0x14A0000u  // 16 KB
#define WS_WNT   0x14A4000u  // 16 KB
// total ~21.7 MB

__device__ __forceinline__ unsigned short f2bf(float f) {
    unsigned u = __builtin_bit_cast(unsigned, f);
    u = (u + 0x7fffu + ((u >> 16) & 1u)) >> 16;   // RNE
    return (unsigned short)u;
}

// ---------------- prep: bf16-cast W_edge, transpose the small weights ----------------
__global__ void prep_kernel(const float* __restrict__ W_edge,
                            const float* __restrict__ W_preagg,
                            const float* __restrict__ W_self,
                            const float* __restrict__ W_neigh,
                            unsigned short* __restrict__ wbf,
                            float* __restrict__ wpreT,
                            float* __restrict__ wsT,
                            float* __restrict__ wnT) {
    int i = blockIdx.x * 256 + threadIdx.x;
    if (i < FOUT * FOUT * EDIM) wbf[i] = f2bf(W_edge[i]);            // 131072
    if (i < FOUT * FIN) {                                            // 16384
        int o = i >> 8, k = i & 255;
        wpreT[k * FOUT + o] = W_preagg[i];
    }
    if (i < FOUT * FOUT) {                                           // 4096
        int o = i >> 6, k = i & 63;
        wsT[k * FOUT + o] = W_self[i];
        wnT[k * FOUT + o] = W_neigh[i];
    }
}

// ---------------- count: deg histogram + per-edge rank ----------------
__global__ void count_kernel(const int* __restrict__ dst,
                             int* __restrict__ deg,
                             int* __restrict__ rank) {
    int e = blockIdx.x * 256 + threadIdx.x;
    rank[e] = atomicAdd(deg + dst[e], 1);
}

// ---------------- scan: exclusive prefix sum of deg[8192] -> off ----------------
__global__ __launch_bounds__(256) void scan_kernel(const int* __restrict__ deg,
                                                   int* __restrict__ off) {
    __shared__ int wsum[4];
    int t = threadIdx.x, lane = t & 63, w = t >> 6;
    int base = t * 32;
    int loc[32];
    int s = 0;
    #pragma unroll
    for (int i = 0; i < 32; ++i) { loc[i] = s; s += deg[base + i]; }
    // wave-inclusive scan of per-thread totals
    int v = s;
    #pragma unroll
    for (int d = 1; d < 64; d <<= 1) {
        int u = __shfl_up(v, d);
        if (lane >= d) v += u;
    }
    if (lane == 63) wsum[w] = v;          // wave total
    int threadExcl = v - s;
    __syncthreads();
    int wexcl = 0;
    for (int i = 0; i < w; ++i) wexcl += wsum[i];
    int tbase = wexcl + threadExcl;
    #pragma unroll
    for (int i = 0; i < 32; ++i) off[base + i] = tbase + loc[i];
}

// ---------------- preagg: hn = relu(h_neigh @ Wp^T), hs = relu(h_self @ Wp^T) --------
__global__ __launch_bounds__(256) void preagg_kernel(const float* __restrict__ h_neigh,
                                                     const float* __restrict__ h_self,
                                                     const float* __restrict__ wpreT,
                                                     float* __restrict__ hn,
                                                     float* __restrict__ hs) {
    __shared__ float hrow[4 * FIN];           // 4 rows x 256
    const float* srcp = blockIdx.y ? h_self : h_neigh;
    float* outp = blockIdx.y ? hs : hn;
    int t = threadIdx.x;
    int row0 = blockIdx.x * 4;
    reinterpret_cast<float4*>(hrow)[t] =
        reinterpret_cast<const float4*>(srcp + (size_t)row0 * FIN)[t];
    __syncthreads();
    int r = t >> 6, o = t & 63;
    const float* hr = hrow + r * FIN;
    float acc = 0.f;
    #pragma unroll 8
    for (int k = 0; k < FIN; ++k)
        acc = fmaf(hr[k], wpreT[k * FOUT + o], acc);
    outp[(size_t)(row0 + r) * FOUT + o] = fmaxf(acc, 0.f);
}

// ---------------- edge: fused edge-MLP GEMM + relu + i-sum + u_mul_e + CSR store ----
// wave = 32 edges (2 MFMA M-tiles); block = 4 waves = 128 edges; grid = 512
#define CHUNK_NB 64

__global__ __launch_bounds__(256, 2) void edge_kernel(
    const float* __restrict__ ef,
    const unsigned short* __restrict__ wbf,
    const float* __restrict__ b_edge,
    const float* __restrict__ hn,
    const int* __restrict__ src,
    const int* __restrict__ dst,
    const int* __restrict__ off,
    const int* __restrict__ rank,
    float* __restrict__ msg) {
    __shared__ __align__(16) unsigned short bsm[CHUNK_NB * 16 * EDIM];   // 64 KB
    int tid = threadIdx.x;
    int wave = tid >> 6, lane = tid & 63;
    int rowm = lane & 15, kc = lane >> 4, k0 = kc * 8;
    int e0 = blockIdx.x * 128 + wave * 32;

    // A fragments: lane holds ef[row = e0+t*16+(lane&15)][k = (lane>>4)*8 .. +8)
    bf16x8 a[2];
    #pragma unroll
    for (int t = 0; t < 2; ++t) {
        const float* p = ef + (size_t)(e0 + t * 16 + rowm) * EDIM + k0;
        float4 v0 = reinterpret_cast<const float4*>(p)[0];
        float4 v1 = reinterpret_cast<const float4*>(p)[1];
        bf16x8 aa;
        aa[0] = (short)f2bf(v0.x); aa[1] = (short)f2bf(v0.y);
        aa[2] = (short)f2bf(v0.z); aa[3] = (short)f2bf(v0.w);
        aa[4] = (short)f2bf(v1.x); aa[5] = (short)f2bf(v1.y);
        aa[6] = (short)f2bf(v1.z); aa[7] = (short)f2bf(v1.w);
        a[t] = aa;
    }

    f32x4 sacc[2][4];
    #pragma unroll
    for (int t = 0; t < 2; ++t)
        #pragma unroll
        for (int j = 0; j < 4; ++j)
            sacc[t][j] = f32x4{0.f, 0.f, 0.f, 0.f};

    for (int ch = 0; ch < 4; ++ch) {
        __syncthreads();
        {   // stage 64KB of W_edge(bf16): coalesced 16B per thread x16
            const u32x4* g = reinterpret_cast<const u32x4*>(wbf) + ch * 4096;
            u32x4* l = reinterpret_cast<u32x4*>(bsm);
            #pragma unroll
            for (int it = 0; it < 16; ++it)
                l[tid + 256 * it] = g[tid + 256 * it];
        }
        __syncthreads();
        const float* bias_p = b_edge + ch * (CHUNK_NB * 16) + rowm;
        for (int nbl = 0; nbl < CHUNK_NB; nbl += 4) {
            #pragma unroll
            for (int u = 0; u < 4; ++u) {
                bf16x8 b = *reinterpret_cast<const bf16x8*>(
                    bsm + ((nbl + u) * 16 + rowm) * EDIM + k0);
                float bias = bias_p[(nbl + u) * 16];
                f32x4 cin = {bias, bias, bias, bias};   // bias folded into C operand
                #pragma unroll
                for (int t = 0; t < 2; ++t) {
                    f32x4 d = __builtin_amdgcn_mfma_f32_16x16x32_bf16(a[t], b, cin, 0, 0, 0);
                    sacc[t][u][0] += fmaxf(d[0], 0.f);
                    sacc[t][u][1] += fmaxf(d[1], 0.f);
                    sacc[t][u][2] += fmaxf(d[2], 0.f);
                    sacc[t][u][3] += fmaxf(d[3], 0.f);
                }
            }
        }
    }

    // CSR scatter: C/D layout col=lane&15, row=(lane>>4)*4+reg
    #pragma unroll
    for (int t = 0; t < 2; ++t) {
        #pragma unroll
        for (int r = 0; r < 4; ++r) {
            int e = e0 + t * 16 + kc * 4 + r;
            int se = src[e], de = dst[e];
            size_t p = (size_t)(off[de] + rank[e]) * FOUT;
            #pragma unroll
            for (int jb = 0; jb < 4; ++jb) {
                int j = jb * 16 + rowm;
                msg[p + j] = sacc[t][jb][r] * hn[(size_t)se * FOUT + j];  // 64B per 1/4-wave
            }
        }
    }
}

// ---------------- final: neigh = mean(msg rows); z = relu(relu(hs@Ws^T)+relu(neigh@Wn^T))
__global__ __launch_bounds__(256) void final_kernel(
    const float* __restrict__ hs,
    const float* __restrict__ msg,
    const int* __restrict__ deg,
    const int* __restrict__ off,
    const float* __restrict__ wsT,
    const float* __restrict__ wnT,
    float* __restrict__ out) {
    __shared__ float sm[4][2][FOUT];
    int t = threadIdx.x, w = t >> 6, lane = t & 63;
    int n = blockIdx.x * 4 + w;
    int o0 = off[n], d = deg[n];
    float acc = 0.f;
    for (int i = 0; i < d; ++i)
        acc += msg[(size_t)(o0 + i) * FOUT + lane];   // 256B/wave contiguous
    float neigh = acc / fmaxf((float)d, 1.f);
    sm[w][0][lane] = neigh;
    sm[w][1][lane] = hs[(size_t)n * FOUT + lane];
    __syncthreads();
    float a1 = 0.f, a2 = 0.f;
    #pragma unroll 8
    for (int k = 0; k < FOUT; ++k) {
        a1 = fmaf(sm[w][1][k], wsT[k * FOUT + lane], a1);
        a2 = fmaf(sm[w][0][k], wnT[k * FOUT + lane], a2);
    }
    out[(size_t)n * FOUT + lane] = fmaxf(fmaxf(a1, 0.f) + fmaxf(a2, 0.f), 0.f);
}

extern "C" void kernel_launch(void* const* d_in, const int* in_sizes, int n_in,
                              void* d_out, int out_size, void* d_ws, size_t ws_size,
                              hipStream_t stream) {
    const float* h_neigh  = (const float*)d_in[0];
    const float* h_self   = (const float*)d_in[1];
    const float* ef       = (const float*)d_in[2];
    const float* W_preagg = (const float*)d_in[3];
    const float* W_self   = (const float*)d_in[4];
    const float* W_neigh  = (const float*)d_in[5];
    const float* W_edge   = (const float*)d_in[6];
    const float* b_edge   = (const float*)d_in[7];
    const int*   src      = (const int*)d_in[8];
    const int*   dst      = (const int*)d_in[9];
    float* out = (float*)d_out;
    char* ws = (char*)d_ws;

    float* hn    = (float*)(ws + WS_HN);
    float* hs    = (float*)(ws + WS_HS);
    float* msg   = (float*)(ws + WS_MSG);
    int*   deg   = (int*)(ws + WS_DEG);
    int*   off   = (int*)(ws + WS_OFF);
    int*   rank  = (int*)(ws + WS_RANK);
    unsigned short* wbf = (unsigned short*)(ws + WS_WBF);
    float* wpreT = (float*)(ws + WS_WPRET);
    float* wsT   = (float*)(ws + WS_WST);
    float* wnT   = (float*)(ws + WS_WNT);

    // zero deg every call (harness does not re-poison between replays)
    hipMemsetAsync(ws + WS_DEG, 0, 0x8000, stream);

    prep_kernel<<<512, 256, 0, stream>>>(W_edge, W_preagg, W_self, W_neigh,
                                         wbf, wpreT, wsT, wnT);
    count_kernel<<<NEDGES / 256, 256, 0, stream>>>(dst, deg, rank);
    scan_kernel<<<1, 256, 0, stream>>>(deg, off);
    preagg_kernel<<<dim3(2048, 2), 256, 0, stream>>>(h_neigh, h_self, wpreT, hn, hs);
    edge_kernel<<<512, 256, 0, stream>>>(ef, wbf, b_edge, hn, src, dst, off, rank, msg);
    final_kernel<<<NNODES / 4, 256, 0, stream>>>(hs, msg, deg, off, wsT, wnT, out);
}

// Round 3
// 133.857 us; speedup vs baseline: 1.6435x; 1.6219x over previous
//
#include <hip/hip_runtime.h>
#include <hip/hip_bf16.h>

typedef __attribute__((ext_vector_type(8))) short bf16x8;
typedef __attribute__((ext_vector_type(4))) float f32x4;
typedef __attribute__((ext_vector_type(4))) unsigned int u32x4;

#define NNODES 8192
#define NEDGES 65536
#define FIN 256
#define FOUT 64
#define EDIM 32

// workspace byte offsets
#define WS_HN    0x000000u   // 2 MB
#define WS_HS    0x200000u   // 2 MB
#define WS_MSG   0x400000u   // 16 MB (edge-order GEMM output, post u_mul-free)
#define WS_DEG   0x1400000u  // 32 KB
#define WS_OFF   0x1408000u  // 32 KB
#define WS_RANK  0x1410000u  // 256 KB
#define WS_PERM  0x1450000u  // 256 KB (slot -> edge id)
#define WS_GSRC  0x1490000u  // 256 KB (slot -> src node)
#define WS_WBF   0x14D0000u  // 256 KB bf16 W_edge
#define WS_WPRET 0x1510000u  // 64 KB
#define WS_WST   0x1520000u  // 16 KB
#define WS_WNT   0x1524000u  // 16 KB

__device__ __forceinline__ unsigned short f2bf(float f) {
    unsigned u = __builtin_bit_cast(unsigned, f);
    u = (u + 0x7fffu + ((u >> 16) & 1u)) >> 16;   // RNE
    return (unsigned short)u;
}

// ---------------- prep ----------------
__global__ void prep_kernel(const float* __restrict__ W_edge,
                            const float* __restrict__ W_preagg,
                            const float* __restrict__ W_self,
                            const float* __restrict__ W_neigh,
                            unsigned short* __restrict__ wbf,
                            float* __restrict__ wpreT,
                            float* __restrict__ wsT,
                            float* __restrict__ wnT) {
    int i = blockIdx.x * 256 + threadIdx.x;
    if (i < FOUT * FOUT * EDIM) wbf[i] = f2bf(W_edge[i]);
    if (i < FOUT * FIN) {
        int o = i >> 8, k = i & 255;
        wpreT[k * FOUT + o] = W_preagg[i];
    }
    if (i < FOUT * FOUT) {
        int o = i >> 6, k = i & 63;
        wsT[k * FOUT + o] = W_self[i];
        wnT[k * FOUT + o] = W_neigh[i];
    }
}

// ---------------- count: deg histogram + per-edge rank ----------------
__global__ void count_kernel(const int* __restrict__ dst,
                             int* __restrict__ deg,
                             int* __restrict__ rank) {
    int e = blockIdx.x * 256 + threadIdx.x;
    rank[e] = atomicAdd(deg + dst[e], 1);
}

// ---------------- scan: exclusive prefix sum of deg[8192] -> off ----------------
__global__ __launch_bounds__(256) void scan_kernel(const int* __restrict__ deg,
                                                   int* __restrict__ off) {
    __shared__ int wsum[4];
    int t = threadIdx.x, lane = t & 63, w = t >> 6;
    int base = t * 32;
    int loc[32];
    int s = 0;
    #pragma unroll
    for (int i = 0; i < 32; ++i) { loc[i] = s; s += deg[base + i]; }
    int v = s;
    #pragma unroll
    for (int d = 1; d < 64; d <<= 1) {
        int u = __shfl_up(v, d);
        if (lane >= d) v += u;
    }
    if (lane == 63) wsum[w] = v;
    int threadExcl = v - s;
    __syncthreads();
    int wexcl = 0;
    for (int i = 0; i < w; ++i) wexcl += wsum[i];
    int tbase = wexcl + threadExcl;
    #pragma unroll
    for (int i = 0; i < 32; ++i) off[base + i] = tbase + loc[i];
}

// ---------------- fill: slot -> (edge id, src node) ----------------
__global__ void fill_kernel(const int* __restrict__ src,
                            const int* __restrict__ dst,
                            const int* __restrict__ off,
                            const int* __restrict__ rank,
                            int* __restrict__ perm,
                            int* __restrict__ gsrc) {
    int e = blockIdx.x * 256 + threadIdx.x;
    int slot = off[dst[e]] + rank[e];
    perm[slot] = e;
    gsrc[slot] = src[e];
}

// ---------------- preagg ----------------
__global__ __launch_bounds__(256) void preagg_kernel(const float* __restrict__ h_neigh,
                                                     const float* __restrict__ h_self,
                                                     const float* __restrict__ wpreT,
                                                     float* __restrict__ hn,
                                                     float* __restrict__ hs) {
    __shared__ float hrow[4 * FIN];
    const float* srcp = blockIdx.y ? h_self : h_neigh;
    float* outp = blockIdx.y ? hs : hn;
    int t = threadIdx.x;
    int row0 = blockIdx.x * 4;
    reinterpret_cast<float4*>(hrow)[t] =
        reinterpret_cast<const float4*>(srcp + (size_t)row0 * FIN)[t];
    __syncthreads();
    int r = t >> 6, o = t & 63;
    const float* hr = hrow + r * FIN;
    float acc = 0.f;
    #pragma unroll 8
    for (int k = 0; k < FIN; ++k)
        acc = fmaf(hr[k], wpreT[k * FOUT + o], acc);
    outp[(size_t)(row0 + r) * FOUT + o] = fmaxf(acc, 0.f);
}

// ---------------- edge_gemm: pure dense GEMM + relu + i-fold, sequential in/out ----
// wave = 64 edges (4 M-tiles, B-frag reused 4x); block = 2 waves = 128 edges;
// grid = 512 (2 blocks/CU, chunk barriers stagger). W staged 4 x 64KB LDS chunks.
__global__ __launch_bounds__(128) void edge_gemm_kernel(
    const float* __restrict__ ef,
    const unsigned short* __restrict__ wbf,
    const float* __restrict__ b_edge,
    float* __restrict__ msg) {
    __shared__ __align__(16) unsigned short bsm[32768];   // 64 KB: 1024 cols x 32 k
    int tid = threadIdx.x;
    int wave = tid >> 6, lane = tid & 63;
    int rowm = lane & 15, kc = lane >> 4, k0 = kc * 8;
    int e0 = blockIdx.x * 128 + wave * 64;

    // A fragments: lane holds ef[e0 + t*16 + rowm][k0 .. k0+8)
    bf16x8 a[4];
    #pragma unroll
    for (int t = 0; t < 4; ++t) {
        const float* p = ef + (size_t)(e0 + t * 16 + rowm) * EDIM + k0;
        float4 v0 = reinterpret_cast<const float4*>(p)[0];
        float4 v1 = reinterpret_cast<const float4*>(p)[1];
        bf16x8 aa;
        aa[0] = (short)f2bf(v0.x); aa[1] = (short)f2bf(v0.y);
        aa[2] = (short)f2bf(v0.z); aa[3] = (short)f2bf(v0.w);
        aa[4] = (short)f2bf(v1.x); aa[5] = (short)f2bf(v1.y);
        aa[6] = (short)f2bf(v1.z); aa[7] = (short)f2bf(v1.w);
        a[t] = aa;
    }

    f32x4 sacc[4][4];
    #pragma unroll
    for (int t = 0; t < 4; ++t)
        #pragma unroll
        for (int j = 0; j < 4; ++j)
            sacc[t][j] = f32x4{0.f, 0.f, 0.f, 0.f};
    const f32x4 z4 = {0.f, 0.f, 0.f, 0.f};

    for (int ch = 0; ch < 4; ++ch) {
        __syncthreads();
        {   // stage 64KB chunk: 128 threads x 16B x 32 iters, coalesced
            const u32x4* g = reinterpret_cast<const u32x4*>(wbf) + ch * 4096;
            u32x4* l = reinterpret_cast<u32x4*>(bsm);
            #pragma unroll
            for (int it = 0; it < 32; ++it)
                l[tid + 128 * it] = g[tid + 128 * it];
        }
        __syncthreads();
        const float* bias_p = b_edge + ch * 1024 + rowm;
        for (int nbl = 0; nbl < 64; nbl += 4) {
            #pragma unroll
            for (int u = 0; u < 4; ++u) {
                bf16x8 b = *reinterpret_cast<const bf16x8*>(
                    bsm + ((nbl + u) * 16 + rowm) * EDIM + k0);
                float bias = bias_p[(nbl + u) * 16];
                f32x4 cin = {bias, bias, bias, bias};
                #pragma unroll
                for (int t = 0; t < 4; ++t) {
                    f32x4 d = __builtin_amdgcn_mfma_f32_16x16x32_bf16(a[t], b, cin, 0, 0, 0);
                    sacc[t][u] += __builtin_elementwise_max(d, z4);   // relu + i-fold
                }
            }
        }
    }

    // sequential store: wave covers msg[e0 .. e0+64) = 16 KB contiguous
    #pragma unroll
    for (int t = 0; t < 4; ++t) {
        #pragma unroll
        for (int r = 0; r < 4; ++r) {
            size_t base = (size_t)(e0 + t * 16 + kc * 4 + r) * FOUT;
            #pragma unroll
            for (int jb = 0; jb < 4; ++jb)
                msg[base + jb * 16 + rowm] = sacc[t][jb][r];
        }
    }
}

// ---------------- final: gather msg/hn rows per node, mean, two FCs ----------------
__global__ __launch_bounds__(256) void final_kernel(
    const float* __restrict__ hs,
    const float* __restrict__ hn,
    const float* __restrict__ msg,
    const int* __restrict__ deg,
    const int* __restrict__ off,
    const int* __restrict__ perm,
    const int* __restrict__ gsrc,
    const float* __restrict__ wsT,
    const float* __restrict__ wnT,
    float* __restrict__ out) {
    __shared__ float sm[4][2][FOUT];
    int t = threadIdx.x, w = t >> 6, lane = t & 63;
    int n = blockIdx.x * 4 + w;
    int o0 = off[n], d = deg[n];
    float acc = 0.f;
    int i = 0;
    for (; i + 2 <= d; i += 2) {
        int ea = perm[o0 + i], sa = gsrc[o0 + i];
        int eb = perm[o0 + i + 1], sb = gsrc[o0 + i + 1];
        float ma = msg[(size_t)ea * FOUT + lane];
        float ha = hn[(size_t)sa * FOUT + lane];
        float mb = msg[(size_t)eb * FOUT + lane];
        float hb = hn[(size_t)sb * FOUT + lane];
        acc = fmaf(ma, ha, acc);
        acc = fmaf(mb, hb, acc);
    }
    if (i < d) {
        int ea = perm[o0 + i], sa = gsrc[o0 + i];
        acc = fmaf(msg[(size_t)ea * FOUT + lane], hn[(size_t)sa * FOUT + lane], acc);
    }
    float neigh = acc / fmaxf((float)d, 1.f);
    sm[w][0][lane] = neigh;
    sm[w][1][lane] = hs[(size_t)n * FOUT + lane];
    __syncthreads();
    float a1 = 0.f, a2 = 0.f;
    #pragma unroll 8
    for (int k = 0; k < FOUT; ++k) {
        a1 = fmaf(sm[w][1][k], wsT[k * FOUT + lane], a1);
        a2 = fmaf(sm[w][0][k], wnT[k * FOUT + lane], a2);
    }
    out[(size_t)n * FOUT + lane] = fmaxf(fmaxf(a1, 0.f) + fmaxf(a2, 0.f), 0.f);
}

extern "C" void kernel_launch(void* const* d_in, const int* in_sizes, int n_in,
                              void* d_out, int out_size, void* d_ws, size_t ws_size,
                              hipStream_t stream) {
    const float* h_neigh  = (const float*)d_in[0];
    const float* h_self   = (const float*)d_in[1];
    const float* ef       = (const float*)d_in[2];
    const float* W_preagg = (const float*)d_in[3];
    const float* W_self   = (const float*)d_in[4];
    const float* W_neigh  = (const float*)d_in[5];
    const float* W_edge   = (const float*)d_in[6];
    const float* b_edge   = (const float*)d_in[7];
    const int*   src      = (const int*)d_in[8];
    const int*   dst      = (const int*)d_in[9];
    float* out = (float*)d_out;
    char* ws = (char*)d_ws;

    float* hn    = (float*)(ws + WS_HN);
    float* hs    = (float*)(ws + WS_HS);
    float* msg   = (float*)(ws + WS_MSG);
    int*   deg   = (int*)(ws + WS_DEG);
    int*   off   = (int*)(ws + WS_OFF);
    int*   rank  = (int*)(ws + WS_RANK);
    int*   perm  = (int*)(ws + WS_PERM);
    int*   gsrc  = (int*)(ws + WS_GSRC);
    unsigned short* wbf = (unsigned short*)(ws + WS_WBF);
    float* wpreT = (float*)(ws + WS_WPRET);
    float* wsT   = (float*)(ws + WS_WST);
    float* wnT   = (float*)(ws + WS_WNT);

    // zero deg every call (count accumulates via atomics)
    hipMemsetAsync(ws + WS_DEG, 0, 0x8000, stream);

    prep_kernel<<<512, 256, 0, stream>>>(W_edge, W_preagg, W_self, W_neigh,
                                         wbf, wpreT, wsT, wnT);
    count_kernel<<<NEDGES / 256, 256, 0, stream>>>(dst, deg, rank);
    scan_kernel<<<1, 256, 0, stream>>>(deg, off);
    fill_kernel<<<NEDGES / 256, 256, 0, stream>>>(src, dst, off, rank, perm, gsrc);
    preagg_kernel<<<dim3(2048, 2), 256, 0, stream>>>(h_neigh, h_self, wpreT, hn, hs);
    edge_gemm_kernel<<<512, 128, 0, stream>>>(ef, wbf, b_edge, msg);
    final_kernel<<<NNODES / 4, 256, 0, stream>>>(hs, hn, msg, deg, off, perm, gsrc,
                                                 wsT, wnT, out);
}

// Round 4
// 100.620 us; speedup vs baseline: 2.1864x; 1.3303x over previous
//
#include <hip/hip_runtime.h>
#include <hip/hip_bf16.h>

typedef __attribute__((ext_vector_type(8))) short bf16x8;
typedef __attribute__((ext_vector_type(4))) float f32x4;
typedef __attribute__((ext_vector_type(4))) unsigned int u32x4;

#define NNODES 8192
#define NEDGES 65536
#define FIN 256
#define FOUT 64
#define EDIM 32

// workspace byte offsets
#define WS_HN    0x000000u   // 2 MB
#define WS_HS    0x200000u   // 2 MB
#define WS_MSG   0x400000u   // 16 MB (edge-order GEMM output s[e,j])
#define WS_DEG   0x1400000u  // 32 KB
#define WS_OFF   0x1408000u  // 32 KB
#define WS_RANK  0x1410000u  // 256 KB
#define WS_PERM  0x1450000u  // 256 KB (slot -> edge id)
#define WS_GSRC  0x1490000u  // 256 KB (slot -> src node)
#define WS_WBF   0x14D0000u  // 256 KB bf16 W_edge
#define WS_WPRET 0x1510000u  // 64 KB
#define WS_WST   0x1520000u  // 16 KB
#define WS_WNT   0x1524000u  // 16 KB

__device__ __forceinline__ unsigned short f2bf(float f) {
    unsigned u = __builtin_bit_cast(unsigned, f);
    u = (u + 0x7fffu + ((u >> 16) & 1u)) >> 16;   // RNE
    return (unsigned short)u;
}

// ---------------- prep ----------------
__global__ void prep_kernel(const float* __restrict__ W_edge,
                            const float* __restrict__ W_preagg,
                            const float* __restrict__ W_self,
                            const float* __restrict__ W_neigh,
                            unsigned short* __restrict__ wbf,
                            float* __restrict__ wpreT,
                            float* __restrict__ wsT,
                            float* __restrict__ wnT) {
    int i = blockIdx.x * 256 + threadIdx.x;
    if (i < FOUT * FOUT * EDIM) wbf[i] = f2bf(W_edge[i]);
    if (i < FOUT * FIN) {
        int o = i >> 8, k = i & 255;
        wpreT[k * FOUT + o] = W_preagg[i];
    }
    if (i < FOUT * FOUT) {
        int o = i >> 6, k = i & 63;
        wsT[k * FOUT + o] = W_self[i];
        wnT[k * FOUT + o] = W_neigh[i];
    }
}

// ---------------- count: deg histogram + per-edge rank ----------------
__global__ void count_kernel(const int* __restrict__ dst,
                             int* __restrict__ deg,
                             int* __restrict__ rank) {
    int e = blockIdx.x * 256 + threadIdx.x;
    rank[e] = atomicAdd(deg + dst[e], 1);
}

// ---------------- scan: exclusive prefix sum of deg[8192] -> off ----------------
__global__ __launch_bounds__(256) void scan_kernel(const int* __restrict__ deg,
                                                   int* __restrict__ off) {
    __shared__ int wsum[4];
    int t = threadIdx.x, lane = t & 63, w = t >> 6;
    int base = t * 32;
    int loc[32];
    int s = 0;
    #pragma unroll
    for (int i = 0; i < 32; ++i) { loc[i] = s; s += deg[base + i]; }
    int v = s;
    #pragma unroll
    for (int d = 1; d < 64; d <<= 1) {
        int u = __shfl_up(v, d);
        if (lane >= d) v += u;
    }
    if (lane == 63) wsum[w] = v;
    int threadExcl = v - s;
    __syncthreads();
    int wexcl = 0;
    for (int i = 0; i < w; ++i) wexcl += wsum[i];
    int tbase = wexcl + threadExcl;
    #pragma unroll
    for (int i = 0; i < 32; ++i) off[base + i] = tbase + loc[i];
}

// ---------------- fill: slot -> (edge id, src node) ----------------
__global__ void fill_kernel(const int* __restrict__ src,
                            const int* __restrict__ dst,
                            const int* __restrict__ off,
                            const int* __restrict__ rank,
                            int* __restrict__ perm,
                            int* __restrict__ gsrc) {
    int e = blockIdx.x * 256 + threadIdx.x;
    int slot = off[dst[e]] + rank[e];
    perm[slot] = e;
    gsrc[slot] = src[e];
}

// ---------------- preagg: 32 rows/block in LDS, 8 rows/thread register tile ---------
__global__ __launch_bounds__(256) void preagg_kernel(const float* __restrict__ h_neigh,
                                                     const float* __restrict__ h_self,
                                                     const float* __restrict__ wpreT,
                                                     float* __restrict__ hn,
                                                     float* __restrict__ hs) {
    __shared__ float hrow[32 * FIN];          // 32 KB
    const float* srcp = blockIdx.y ? h_self : h_neigh;
    float* outp = blockIdx.y ? hs : hn;
    int t = threadIdx.x;
    size_t row0 = (size_t)blockIdx.x * 32;
    {   // stage 32 rows = 2048 float4
        const float4* g = reinterpret_cast<const float4*>(srcp + row0 * FIN);
        float4* l = reinterpret_cast<float4*>(hrow);
        #pragma unroll
        for (int it = 0; it < 8; ++it)
            l[t + 256 * it] = g[t + 256 * it];
    }
    __syncthreads();
    int o = t & 63, wr = t >> 6;              // wave wr owns rows wr*8..wr*8+8
    float acc[8] = {0.f, 0.f, 0.f, 0.f, 0.f, 0.f, 0.f, 0.f};
    for (int k4 = 0; k4 < FIN; k4 += 4) {
        float w0 = wpreT[(k4 + 0) * FOUT + o];
        float w1 = wpreT[(k4 + 1) * FOUT + o];
        float w2 = wpreT[(k4 + 2) * FOUT + o];
        float w3 = wpreT[(k4 + 3) * FOUT + o];
        #pragma unroll
        for (int rr = 0; rr < 8; ++rr) {
            float4 h4 = *reinterpret_cast<const float4*>(&hrow[(wr * 8 + rr) * FIN + k4]);
            acc[rr] = fmaf(h4.x, w0, acc[rr]);
            acc[rr] = fmaf(h4.y, w1, acc[rr]);
            acc[rr] = fmaf(h4.z, w2, acc[rr]);
            acc[rr] = fmaf(h4.w, w3, acc[rr]);
        }
    }
    #pragma unroll
    for (int rr = 0; rr < 8; ++rr)
        outp[(row0 + wr * 8 + rr) * FOUT + o] = fmaxf(acc[rr], 0.f);
}

// ---------------- edge_gemm: dense GEMM + relu + i-fold ----------------
// block = 512 thr = 8 waves = 2 edge-halves (mw) x 4 col-quarters (cw)
// wave: 64 edges x 1024 cols {c : c%64 in [cw*16, cw*16+16)} -> j = cw*16+rowm fixed
// W staged in 8 x 32KB LDS chunks shared by all waves; grid 512 -> 16 waves/CU
__global__ __launch_bounds__(512, 4) void edge_gemm_kernel(
    const float* __restrict__ ef,
    const unsigned short* __restrict__ wbf,
    const float* __restrict__ b_edge,
    float* __restrict__ msg) {
    __shared__ __align__(16) unsigned short bsm[16384];   // 32 KB = 512 cols x 32 k
    int tid = threadIdx.x;
    int wave = tid >> 6, lane = tid & 63;
    int rowm = lane & 15, kc = lane >> 4, k0 = kc * 8;
    int mw = wave >> 2, cw = wave & 3;
    int e0 = blockIdx.x * 128 + mw * 64;

    // A fragments: lane holds ef[e0 + t*16 + rowm][k0 .. k0+8)
    bf16x8 a[4];
    #pragma unroll
    for (int t = 0; t < 4; ++t) {
        const float* p = ef + (size_t)(e0 + t * 16 + rowm) * EDIM + k0;
        float4 v0 = reinterpret_cast<const float4*>(p)[0];
        float4 v1 = reinterpret_cast<const float4*>(p)[1];
        bf16x8 aa;
        aa[0] = (short)f2bf(v0.x); aa[1] = (short)f2bf(v0.y);
        aa[2] = (short)f2bf(v0.z); aa[3] = (short)f2bf(v0.w);
        aa[4] = (short)f2bf(v1.x); aa[5] = (short)f2bf(v1.y);
        aa[6] = (short)f2bf(v1.z); aa[7] = (short)f2bf(v1.w);
        a[t] = aa;
    }

    f32x4 sacc[4];
    #pragma unroll
    for (int t = 0; t < 4; ++t) sacc[t] = f32x4{0.f, 0.f, 0.f, 0.f};
    const f32x4 z4 = {0.f, 0.f, 0.f, 0.f};

    for (int s = 0; s < 8; ++s) {
        __syncthreads();
        {   // stage 32 KB chunk: 512 thr x 16 B x 4 iters, coalesced
            const u32x4* g = reinterpret_cast<const u32x4*>(wbf) + s * 2048;
            u32x4* l = reinterpret_cast<u32x4*>(bsm);
            #pragma unroll
            for (int it = 0; it < 4; ++it)
                l[tid + 512 * it] = g[tid + 512 * it];
        }
        __syncthreads();
        const float* bias_p = b_edge + s * 512 + cw * 16 + rowm;
        #pragma unroll
        for (int il = 0; il < 8; ++il) {
            int col_local = il * 64 + cw * 16 + rowm;
            bf16x8 b = *reinterpret_cast<const bf16x8*>(
                reinterpret_cast<const char*>(bsm) + col_local * 64 + kc * 16);
            float bias = bias_p[il * 64];
            f32x4 cin = {bias, bias, bias, bias};
            #pragma unroll
            for (int t = 0; t < 4; ++t) {
                f32x4 d = __builtin_amdgcn_mfma_f32_16x16x32_bf16(a[t], b, cin, 0, 0, 0);
                sacc[t] += __builtin_elementwise_max(d, z4);   // relu + i-fold
            }
        }
    }

    // store: j = cw*16 + rowm ; C/D layout row = kc*4 + r
    #pragma unroll
    for (int t = 0; t < 4; ++t) {
        #pragma unroll
        for (int r = 0; r < 4; ++r) {
            size_t e = (size_t)(e0 + t * 16 + kc * 4 + r);
            msg[e * FOUT + cw * 16 + rowm] = sacc[t][r];
        }
    }
}

// ---------------- final: gather msg/hn rows per node, mean, two FCs ----------------
__global__ __launch_bounds__(256) void final_kernel(
    const float* __restrict__ hs,
    const float* __restrict__ hn,
    const float* __restrict__ msg,
    const int* __restrict__ deg,
    const int* __restrict__ off,
    const int* __restrict__ perm,
    const int* __restrict__ gsrc,
    const float* __restrict__ wsT,
    const float* __restrict__ wnT,
    float* __restrict__ out) {
    __shared__ float sm[4][2][FOUT];
    int t = threadIdx.x, w = t >> 6, lane = t & 63;
    int n = blockIdx.x * 4 + w;
    int o0 = off[n], d = deg[n];
    float acc = 0.f;
    int i = 0;
    for (; i + 2 <= d; i += 2) {
        int ea = perm[o0 + i], sa = gsrc[o0 + i];
        int eb = perm[o0 + i + 1], sb = gsrc[o0 + i + 1];
        float ma = msg[(size_t)ea * FOUT + lane];
        float ha = hn[(size_t)sa * FOUT + lane];
        float mb = msg[(size_t)eb * FOUT + lane];
        float hb = hn[(size_t)sb * FOUT + lane];
        acc = fmaf(ma, ha, acc);
        acc = fmaf(mb, hb, acc);
    }
    if (i < d) {
        int ea = perm[o0 + i], sa = gsrc[o0 + i];
        acc = fmaf(msg[(size_t)ea * FOUT + lane], hn[(size_t)sa * FOUT + lane], acc);
    }
    float neigh = acc / fmaxf((float)d, 1.f);
    sm[w][0][lane] = neigh;
    sm[w][1][lane] = hs[(size_t)n * FOUT + lane];
    __syncthreads();
    float a1 = 0.f, a2 = 0.f;
    #pragma unroll 8
    for (int k = 0; k < FOUT; ++k) {
        a1 = fmaf(sm[w][1][k], wsT[k * FOUT + lane], a1);
        a2 = fmaf(sm[w][0][k], wnT[k * FOUT + lane], a2);
    }
    out[(size_t)n * FOUT + lane] = fmaxf(fmaxf(a1, 0.f) + fmaxf(a2, 0.f), 0.f);
}

extern "C" void kernel_launch(void* const* d_in, const int* in_sizes, int n_in,
                              void* d_out, int out_size, void* d_ws, size_t ws_size,
                              hipStream_t stream) {
    const float* h_neigh  = (const float*)d_in[0];
    const float* h_self   = (const float*)d_in[1];
    const float* ef       = (const float*)d_in[2];
    const float* W_preagg = (const float*)d_in[3];
    const float* W_self   = (const float*)d_in[4];
    const float* W_neigh  = (const float*)d_in[5];
    const float* W_edge   = (const float*)d_in[6];
    const float* b_edge   = (const float*)d_in[7];
    const int*   src      = (const int*)d_in[8];
    const int*   dst      = (const int*)d_in[9];
    float* out = (float*)d_out;
    char* ws = (char*)d_ws;

    float* hn    = (float*)(ws + WS_HN);
    float* hs    = (float*)(ws + WS_HS);
    float* msg   = (float*)(ws + WS_MSG);
    int*   deg   = (int*)(ws + WS_DEG);
    int*   off   = (int*)(ws + WS_OFF);
    int*   rank  = (int*)(ws + WS_RANK);
    int*   perm  = (int*)(ws + WS_PERM);
    int*   gsrc  = (int*)(ws + WS_GSRC);
    unsigned short* wbf = (unsigned short*)(ws + WS_WBF);
    float* wpreT = (float*)(ws + WS_WPRET);
    float* wsT   = (float*)(ws + WS_WST);
    float* wnT   = (float*)(ws + WS_WNT);

    // zero deg every call (count accumulates via atomics)
    hipMemsetAsync(ws + WS_DEG, 0, 0x8000, stream);

    prep_kernel<<<512, 256, 0, stream>>>(W_edge, W_preagg, W_self, W_neigh,
                                         wbf, wpreT, wsT, wnT);
    count_kernel<<<NEDGES / 256, 256, 0, stream>>>(dst, deg, rank);
    scan_kernel<<<1, 256, 0, stream>>>(deg, off);
    fill_kernel<<<NEDGES / 256, 256, 0, stream>>>(src, dst, off, rank, perm, gsrc);
    preagg_kernel<<<dim3(256, 2), 256, 0, stream>>>(h_neigh, h_self, wpreT, hn, hs);
    edge_gemm_kernel<<<512, 512, 0, stream>>>(ef, wbf, b_edge, msg);
    final_kernel<<<NNODES / 4, 256, 0, stream>>>(hs, hn, msg, deg, off, perm, gsrc,
                                                 wsT, wnT, out);
}

// Round 5
// 84.571 us; speedup vs baseline: 2.6013x; 1.1898x over previous
//
#include <hip/hip_runtime.h>
#include <hip/hip_bf16.h>

typedef __attribute__((ext_vector_type(8))) short bf16x8;
typedef __attribute__((ext_vector_type(4))) float f32x4;

#define NNODES 8192
#define NEDGES 65536
#define FIN 256
#define FOUT 64
#define EDIM 32

// workspace byte offsets
#define WS_HN    0x000000u   // 2 MB
#define WS_HS    0x200000u   // 2 MB
#define WS_MSG   0x400000u   // 16 MB (edge-order GEMM output s[e,j])
#define WS_DEG   0x1400000u  // 32 KB
#define WS_OFF   0x1408000u  // 32 KB
#define WS_RANK  0x1410000u  // 256 KB
#define WS_PERM  0x1450000u  // 256 KB (slot -> edge id)
#define WS_GSRC  0x1490000u  // 256 KB (slot -> src node)
#define WS_WBF   0x14D0000u  // 256 KB bf16 W_edge
#define WS_WPRET 0x1510000u  // 64 KB
#define WS_WST   0x1520000u  // 16 KB
#define WS_WNT   0x1524000u  // 16 KB

__device__ __forceinline__ unsigned short f2bf(float f) {
    unsigned u = __builtin_bit_cast(unsigned, f);
    u = (u + 0x7fffu + ((u >> 16) & 1u)) >> 16;   // RNE
    return (unsigned short)u;
}

// ---------------- K1a: prep (weight transforms) || count (deg histogram + rank) -----
__global__ __launch_bounds__(256) void prep_count_kernel(
    const float* __restrict__ W_edge,
    const float* __restrict__ W_preagg,
    const float* __restrict__ W_self,
    const float* __restrict__ W_neigh,
    const int* __restrict__ dst,
    unsigned short* __restrict__ wbf,
    float* __restrict__ wpreT,
    float* __restrict__ wsT,
    float* __restrict__ wnT,
    int* __restrict__ deg,
    int* __restrict__ rank) {
    int b = blockIdx.x, t = threadIdx.x;
    if (b < 512) {                       // prep: i in [0, 131072)
        int i = b * 256 + t;
        if (i < FOUT * FOUT * EDIM) wbf[i] = f2bf(W_edge[i]);
        if (i < FOUT * FIN) {
            int o = i >> 8, k = i & 255;
            wpreT[k * FOUT + o] = W_preagg[i];
        }
        if (i < FOUT * FOUT) {
            int o = i >> 6, k = i & 63;
            wsT[k * FOUT + o] = W_self[i];
            wnT[k * FOUT + o] = W_neigh[i];
        }
    } else {                             // count: e in [0, 65536)
        int e = (b - 512) * 256 + t;
        rank[e] = atomicAdd(deg + dst[e], 1);
    }
}

// ---------------- K1b: preagg (relu(h @ Wp^T)) || scan (prefix sum of deg) ----------
__global__ __launch_bounds__(256) void preagg_scan_kernel(
    const float* __restrict__ h_neigh,
    const float* __restrict__ h_self,
    const float* __restrict__ wpreT,
    const int* __restrict__ deg,
    float* __restrict__ hn,
    float* __restrict__ hs,
    int* __restrict__ off) {
    __shared__ float hrow[32 * FIN];          // 32 KB
    __shared__ int wsum[4];
    int b = blockIdx.x, t = threadIdx.x;
    if (b == 512) {                      // scan, single block
        int lane = t & 63, w = t >> 6;
        int base = t * 32;
        int loc[32];
        int s = 0;
        #pragma unroll
        for (int i = 0; i < 32; ++i) { loc[i] = s; s += deg[base + i]; }
        int v = s;
        #pragma unroll
        for (int d = 1; d < 64; d <<= 1) {
            int u = __shfl_up(v, d);
            if (lane >= d) v += u;
        }
        if (lane == 63) wsum[w] = v;
        int threadExcl = v - s;
        __syncthreads();
        int wexcl = 0;
        for (int i = 0; i < w; ++i) wexcl += wsum[i];
        int tbase = wexcl + threadExcl;
        #pragma unroll
        for (int i = 0; i < 32; ++i) off[base + i] = tbase + loc[i];
        return;
    }
    // preagg: b in [0,512), y = b>>8 selects self/neigh, 32 rows/block
    const float* srcp = (b >> 8) ? h_self : h_neigh;
    float* outp = (b >> 8) ? hs : hn;
    size_t row0 = (size_t)(b & 255) * 32;
    {   // stage 32 rows = 2048 float4
        const float4* g = reinterpret_cast<const float4*>(srcp + row0 * FIN);
        float4* l = reinterpret_cast<float4*>(hrow);
        #pragma unroll
        for (int it = 0; it < 8; ++it)
            l[t + 256 * it] = g[t + 256 * it];
    }
    __syncthreads();
    int o = t & 63, wr = t >> 6;              // wave wr owns rows wr*8..wr*8+8
    float acc[8] = {0.f, 0.f, 0.f, 0.f, 0.f, 0.f, 0.f, 0.f};
    for (int k4 = 0; k4 < FIN; k4 += 4) {
        float w0 = wpreT[(k4 + 0) * FOUT + o];
        float w1 = wpreT[(k4 + 1) * FOUT + o];
        float w2 = wpreT[(k4 + 2) * FOUT + o];
        float w3 = wpreT[(k4 + 3) * FOUT + o];
        #pragma unroll
        for (int rr = 0; rr < 8; ++rr) {
            float4 h4 = *reinterpret_cast<const float4*>(&hrow[(wr * 8 + rr) * FIN + k4]);
            acc[rr] = fmaf(h4.x, w0, acc[rr]);
            acc[rr] = fmaf(h4.y, w1, acc[rr]);
            acc[rr] = fmaf(h4.z, w2, acc[rr]);
            acc[rr] = fmaf(h4.w, w3, acc[rr]);
        }
    }
    #pragma unroll
    for (int rr = 0; rr < 8; ++rr)
        outp[(row0 + wr * 8 + rr) * FOUT + o] = fmaxf(acc[rr], 0.f);
}

// ---------------- K3: edge GEMM (no LDS, B direct from L2, depth-4 pipeline) || fill
// edge blocks [0,512): 512 thr = 8 waves = 2 edge-halves (mw) x 4 col-quarters (cw)
// wave: 64 edges, cols c with c%64 in [cw*16,cw*16+16); g in [0,64): col = g*64+colbase
__global__ __launch_bounds__(512, 4) void edge_fill_kernel(
    const float* __restrict__ ef,
    const unsigned short* __restrict__ wbf,
    const float* __restrict__ b_edge,
    const int* __restrict__ src,
    const int* __restrict__ dst,
    const int* __restrict__ off,
    const int* __restrict__ rank,
    float* __restrict__ msg,
    int* __restrict__ perm,
    int* __restrict__ gsrc) {
    int b = blockIdx.x, tid = threadIdx.x;
    if (b >= 512) {                      // fill: e in [0, 65536)
        int e = (b - 512) * 512 + tid;
        int slot = off[dst[e]] + rank[e];
        perm[slot] = e;
        gsrc[slot] = src[e];
        return;
    }
    int wave = tid >> 6, lane = tid & 63;
    int rowm = lane & 15, kc = lane >> 4, k0 = kc * 8;
    int mw = wave >> 2, cw = wave & 3;
    int e0 = b * 128 + mw * 64;
    int colbase = cw * 16 + rowm;

    // A fragments: lane holds ef[e0 + t*16 + rowm][k0 .. k0+8)
    bf16x8 a[4];
    #pragma unroll
    for (int t = 0; t < 4; ++t) {
        const float* p = ef + (size_t)(e0 + t * 16 + rowm) * EDIM + k0;
        float4 v0 = reinterpret_cast<const float4*>(p)[0];
        float4 v1 = reinterpret_cast<const float4*>(p)[1];
        bf16x8 aa;
        aa[0] = (short)f2bf(v0.x); aa[1] = (short)f2bf(v0.y);
        aa[2] = (short)f2bf(v0.z); aa[3] = (short)f2bf(v0.w);
        aa[4] = (short)f2bf(v1.x); aa[5] = (short)f2bf(v1.y);
        aa[6] = (short)f2bf(v1.z); aa[7] = (short)f2bf(v1.w);
        a[t] = aa;
    }

    f32x4 sacc[4];
    #pragma unroll
    for (int t = 0; t < 4; ++t) sacc[t] = f32x4{0.f, 0.f, 0.f, 0.f};
    const f32x4 z4 = {0.f, 0.f, 0.f, 0.f};
    const char* wb = reinterpret_cast<const char*>(wbf);

    // depth-4 software pipeline over g in [0,64), all indices static
    bf16x8 bb[4];
    float bs[4];
    #pragma unroll
    for (int p = 0; p < 4; ++p) {
        bb[p] = *reinterpret_cast<const bf16x8*>(
            wb + ((size_t)(p * 64 + colbase) * 64 + kc * 16));
        bs[p] = b_edge[p * 64 + colbase];
    }
    #pragma unroll
    for (int gb = 0; gb < 64; gb += 4) {
        #pragma unroll
        for (int p = 0; p < 4; ++p) {
            bf16x8 bcur = bb[p];
            float bias = bs[p];
            int gn = gb + 4 + p;
            if (gn < 64) {               // compile-time condition (full unroll)
                bb[p] = *reinterpret_cast<const bf16x8*>(
                    wb + ((size_t)(gn * 64 + colbase) * 64 + kc * 16));
                bs[p] = b_edge[gn * 64 + colbase];
            }
            f32x4 cin = {bias, bias, bias, bias};
            #pragma unroll
            for (int t = 0; t < 4; ++t) {
                f32x4 d = __builtin_amdgcn_mfma_f32_16x16x32_bf16(a[t], bcur, cin, 0, 0, 0);
                sacc[t] += __builtin_elementwise_max(d, z4);   // relu + i-fold
            }
        }
    }

    // store: j = cw*16 + rowm ; C/D layout row = kc*4 + r
    #pragma unroll
    for (int t = 0; t < 4; ++t) {
        #pragma unroll
        for (int r = 0; r < 4; ++r) {
            size_t e = (size_t)(e0 + t * 16 + kc * 4 + r);
            msg[e * FOUT + cw * 16 + rowm] = sacc[t][r];
        }
    }
}

// ---------------- final: gather msg/hn rows per node, mean, two FCs ----------------
__global__ __launch_bounds__(256) void final_kernel(
    const float* __restrict__ hs,
    const float* __restrict__ hn,
    const float* __restrict__ msg,
    const int* __restrict__ deg,
    const int* __restrict__ off,
    const int* __restrict__ perm,
    const int* __restrict__ gsrc,
    const float* __restrict__ wsT,
    const float* __restrict__ wnT,
    float* __restrict__ out) {
    __shared__ float sm[4][2][FOUT];
    int t = threadIdx.x, w = t >> 6, lane = t & 63;
    int n = blockIdx.x * 4 + w;
    int o0 = off[n], d = deg[n];
    float acc = 0.f;
    int i = 0;
    for (; i + 2 <= d; i += 2) {
        int ea = perm[o0 + i], sa = gsrc[o0 + i];
        int eb = perm[o0 + i + 1], sb = gsrc[o0 + i + 1];
        float ma = msg[(size_t)ea * FOUT + lane];
        float ha = hn[(size_t)sa * FOUT + lane];
        float mb = msg[(size_t)eb * FOUT + lane];
        float hb = hn[(size_t)sb * FOUT + lane];
        acc = fmaf(ma, ha, acc);
        acc = fmaf(mb, hb, acc);
    }
    if (i < d) {
        int ea = perm[o0 + i], sa = gsrc[o0 + i];
        acc = fmaf(msg[(size_t)ea * FOUT + lane], hn[(size_t)sa * FOUT + lane], acc);
    }
    float neigh = acc / fmaxf((float)d, 1.f);
    sm[w][0][lane] = neigh;
    sm[w][1][lane] = hs[(size_t)n * FOUT + lane];
    __syncthreads();
    float a1 = 0.f, a2 = 0.f;
    #pragma unroll 8
    for (int k = 0; k < FOUT; ++k) {
        a1 = fmaf(sm[w][1][k], wsT[k * FOUT + lane], a1);
        a2 = fmaf(sm[w][0][k], wnT[k * FOUT + lane], a2);
    }
    out[(size_t)n * FOUT + lane] = fmaxf(fmaxf(a1, 0.f) + fmaxf(a2, 0.f), 0.f);
}

extern "C" void kernel_launch(void* const* d_in, const int* in_sizes, int n_in,
                              void* d_out, int out_size, void* d_ws, size_t ws_size,
                              hipStream_t stream) {
    const float* h_neigh  = (const float*)d_in[0];
    const float* h_self   = (const float*)d_in[1];
    const float* ef       = (const float*)d_in[2];
    const float* W_preagg = (const float*)d_in[3];
    const float* W_self   = (const float*)d_in[4];
    const float* W_neigh  = (const float*)d_in[5];
    const float* W_edge   = (const float*)d_in[6];
    const float* b_edge   = (const float*)d_in[7];
    const int*   src      = (const int*)d_in[8];
    const int*   dst      = (const int*)d_in[9];
    float* out = (float*)d_out;
    char* ws = (char*)d_ws;

    float* hn    = (float*)(ws + WS_HN);
    float* hs    = (float*)(ws + WS_HS);
    float* msg   = (float*)(ws + WS_MSG);
    int*   deg   = (int*)(ws + WS_DEG);
    int*   off   = (int*)(ws + WS_OFF);
    int*   rank  = (int*)(ws + WS_RANK);
    int*   perm  = (int*)(ws + WS_PERM);
    int*   gsrc  = (int*)(ws + WS_GSRC);
    unsigned short* wbf = (unsigned short*)(ws + WS_WBF);
    float* wpreT = (float*)(ws + WS_WPRET);
    float* wsT   = (float*)(ws + WS_WST);
    float* wnT   = (float*)(ws + WS_WNT);

    // zero deg every call (count accumulates via atomics)
    hipMemsetAsync(ws + WS_DEG, 0, 0x8000, stream);

    prep_count_kernel<<<768, 256, 0, stream>>>(W_edge, W_preagg, W_self, W_neigh,
                                               dst, wbf, wpreT, wsT, wnT, deg, rank);
    preagg_scan_kernel<<<513, 256, 0, stream>>>(h_neigh, h_self, wpreT, deg,
                                                hn, hs, off);
    edge_fill_kernel<<<640, 512, 0, stream>>>(ef, wbf, b_edge, src, dst, off, rank,
                                              msg, perm, gsrc);
    final_kernel<<<NNODES / 4, 256, 0, stream>>>(hs, hn, msg, deg, off, perm, gsrc,
                                                 wsT, wnT, out);
}